// Round 10
// baseline (430.440 us; speedup 1.0000x reference)
//
#include <hip/hip_runtime.h>
#include <stdint.h>
#include <math.h>

#define N_ROWS 16384
#define D_DIM  4096
#define E_EXP  128
#define BM     32
#define BKR    128              // k per round
#define KSPLIT 4
#define KCHUNK (D_DIM / KSPLIT) // 1024
#define NR     (KCHUNK / BKR)   // 8 rounds per block
#define TAU    2.5e-4f

typedef short  short8 __attribute__((ext_vector_type(8)));
typedef float  f32x4  __attribute__((ext_vector_type(4)));

__device__ __forceinline__ uint32_t bf16_rne(float f) {
  uint32_t u = __builtin_bit_cast(uint32_t, f);
  return (u + 0x7fffu + ((u >> 16) & 1u)) >> 16;
}

// ---------------- kernel 0: split W into bf16 hi/lo, FRAGMENT-TILED ----------------
// blk = (eg*128 + kc)*2 + hl ; within blk lane l: W[eg*16+(l&15)][kc*32+(l>>4)*8 ..+8]
__global__ __launch_bounds__(256) void k0_split(const float* __restrict__ W,
                                                uint16_t* __restrict__ wt) {
  const int b  = blockIdx.x;       // 256 blocks
  const int t  = threadIdx.x;      // 256 threads
  const int eg  = b >> 5;          // 0..7
  const int kcg = b & 31;
  const int kc  = kcg * 4 + (t >> 6);   // 0..127
  const int lane = t & 63;
  const int e  = eg * 16 + (lane & 15);
  const int k0 = kc * 32 + (lane >> 4) * 8;

  const float* src = W + (size_t)e * D_DIM + k0;
  f32x4 w0 = *(const f32x4*)src;
  f32x4 w1 = *(const f32x4*)(src + 4);
  float wf[8] = {w0[0], w0[1], w0[2], w0[3], w1[0], w1[1], w1[2], w1[3]};

  uint16_t h[8], l[8];
  #pragma unroll
  for (int j = 0; j < 8; ++j) {
    uint32_t hh = bf16_rne(wf[j]);
    float hf = __builtin_bit_cast(float, hh << 16);
    h[j] = (uint16_t)hh;
    l[j] = (uint16_t)bf16_rne(wf[j] - hf);
  }
  const size_t blkh = ((size_t)(eg * 128 + kc) * 2 + 0) * 512;  // elements
  const size_t blkl = ((size_t)(eg * 128 + kc) * 2 + 1) * 512;
  *(short8*)(wt + blkh + lane * 8) = *(const short8*)h;
  *(short8*)(wt + blkl + lane * 8) = *(const short8*)l;
}

// ---------------- kernel 1: K-split split-bf16 MFMA GEMM -> f32 partials ----------------
// 2048 blocks (512 row-tiles x 4 k-chunks), 512 threads = 8 waves, 8 rounds/block.
__global__ __launch_bounds__(512, 8) void k1_main(
    const float* __restrict__ x, const uint16_t* __restrict__ wt,
    float* __restrict__ part)
{
  __shared__ __align__(16) uint8_t smem[32768];   // 2 x 16KB staging

  const int t    = threadIdx.x;
  const int lane = t & 63;
  const int wv   = __builtin_amdgcn_readfirstlane(t >> 6);
  const int bid  = blockIdx.x;
  const int rt   = bid >> 2;       // row tile 0..511
  const int ks   = bid & 3;        // k chunk 0..3
  const int row0 = rt * BM;
  const int kb0  = ks * KCHUNK;

  // ---- X staging map ----
  const int srow = t >> 4;        // 0..31
  const int skg  = t & 15;        // k-group of 8 within 128
  const float* xp = x + (size_t)(row0 + srow) * D_DIM + kb0 + skg * 8;

  // ---- LDS write map ----
  const int s_w = skg >> 2, gg_w = skg & 3, rr_w = srow & 15, rg_w = srow >> 4;
  const int p_w  = gg_w * 16 + (rr_w ^ (gg_w << 1) ^ s_w);
  const int wa_h = (s_w * 4 + rg_w * 2 + 0) * 1024 + p_w * 16;
  const int wa_l = wa_h + 1024;

  // ---- LDS read map ----
  const int ggr = lane >> 4, rrr = lane & 15;
  const int p_r0 = ggr * 16 + (rrr ^ (ggr << 1));   // step s: slot = p_r0 ^ s

  // ---- W tiled fragment pointer ----
  const short8* Wt8 = (const short8*)wt;
  const int ccol = lane & 15;

  f32x4 acc[2] = {};

  // x prefetch 3-deep
  f32x4 xa0, xa1, xb0, xb1, xc0, xc1;
  xa0 = *((const f32x4*)xp + 0); xa1 = *((const f32x4*)xp + 1);
  xb0 = *((const f32x4*)(xp + BKR) + 0); xb1 = *((const f32x4*)(xp + BKR) + 1);
  xc0 = *((const f32x4*)(xp + 2 * BKR) + 0); xc1 = *((const f32x4*)(xp + 2 * BKR) + 1);

  #pragma unroll 2
  for (int r = 0; r < NR; ++r) {
    // 1) W fragments for THIS round (contiguous 1-KB wave loads from L2)
    short8 Wc[8];
    {
      const size_t base = ((size_t)(wv * 128 + ks * 32 + r * 4) * 2) * 64 + lane;
      #pragma unroll
      for (int s = 0; s < 4; ++s) {
        Wc[s * 2 + 0] = Wt8[base + (size_t)(s * 2 + 0) * 64];
        Wc[s * 2 + 1] = Wt8[base + (size_t)(s * 2 + 1) * 64];
      }
    }

    // 2) convert xa -> bf16 h/l, write LDS buf[r&1]
    float xf[8] = {xa0[0], xa0[1], xa0[2], xa0[3], xa1[0], xa1[1], xa1[2], xa1[3]};
    uint32_t hpk[4], lpk[4];
    #pragma unroll
    for (int j = 0; j < 4; ++j) {
      uint32_t h0 = bf16_rne(xf[2*j]), h1 = bf16_rne(xf[2*j+1]);
      float h0f = __builtin_bit_cast(float, h0 << 16);
      float h1f = __builtin_bit_cast(float, h1 << 16);
      uint32_t l0 = bf16_rne(xf[2*j] - h0f), l1 = bf16_rne(xf[2*j+1] - h1f);
      hpk[j] = h0 | (h1 << 16);
      lpk[j] = l0 | (l1 << 16);
    }
    uint8_t* buf = smem + (r & 1) * 16384;
    *(uint4*)(buf + wa_h) = make_uint4(hpk[0], hpk[1], hpk[2], hpk[3]);
    *(uint4*)(buf + wa_l) = make_uint4(lpk[0], lpk[1], lpk[2], lpk[3]);

    // 3) rotate x pipeline; issue load for round r+3
    xa0 = xb0; xa1 = xb1; xb0 = xc0; xb1 = xc1;
    if (r + 3 < NR) {
      const f32x4* np = (const f32x4*)(xp + (size_t)(r + 3) * BKR);
      xc0 = np[0]; xc1 = np[1];
    }

    // 4) LDS writes visible; barrier
    asm volatile("s_waitcnt lgkmcnt(0)" ::: "memory");
    __builtin_amdgcn_s_barrier();

    // 5) MFMA round r: 4 k-steps x 2 row-groups x {hh, lh, hl}
    #pragma unroll
    for (int s = 0; s < 4; ++s) {
      const int pr = p_r0 ^ s;
      const short8 bh = Wc[s * 2 + 0], bl = Wc[s * 2 + 1];
      #pragma unroll
      for (int rg = 0; rg < 2; ++rg) {
        const uint8_t* fb = buf + (s * 4 + rg * 2) * 1024 + pr * 16;
        short8 ah = *(const short8*)fb;
        short8 al = *(const short8*)(fb + 1024);
        acc[rg] = __builtin_amdgcn_mfma_f32_16x16x32_bf16(ah, bh, acc[rg], 0, 0, 0);
        acc[rg] = __builtin_amdgcn_mfma_f32_16x16x32_bf16(al, bh, acc[rg], 0, 0, 0);
        acc[rg] = __builtin_amdgcn_mfma_f32_16x16x32_bf16(ah, bl, acc[rg], 0, 0, 0);
      }
    }
  }

  // ---- epilogue: store partials part[ks][row][e] ----
  float* dst = part + ((size_t)ks * N_ROWS + row0) * E_EXP;
  #pragma unroll
  for (int rg = 0; rg < 2; ++rg)
    #pragma unroll
    for (int i = 0; i < 4; ++i) {
      int row = rg * 16 + ggr * 4 + i;
      int e = wv * 16 + ccol;
      dst[(size_t)row * E_EXP + e] = acc[rg][i];
    }
}

// ---------------- kernel 3: reduce partials + bias + sigmoid + top-3 + flags ----------------
__global__ __launch_bounds__(512) void k3_reduce(
    const float* __restrict__ part, const float* __restrict__ bias,
    float* __restrict__ out, int* __restrict__ flags)
{
  const int t = threadIdx.x;
  const int row = t >> 4, prt = t & 15;     // 32 rows/block, 16 threads/row
  const int grow = blockIdx.x * 32 + row;
  const float* pp = part + (size_t)grow * E_EXP + prt * 8;

  f32x4 s0 = {}, s1 = {};
  #pragma unroll
  for (int ks = 0; ks < KSPLIT; ++ks) {
    const float* q = pp + (size_t)ks * N_ROWS * E_EXP;
    f32x4 a = *(const f32x4*)q;
    f32x4 b = *(const f32x4*)(q + 4);
    s0 += a; s1 += b;
  }
  float lv[8] = {s0[0], s0[1], s0[2], s0[3], s1[0], s1[1], s1[2], s1[3]};

  float l1 = -3e38f, l2 = -3e38f, l3 = -3e38f;
  int   i1 = -1, i2 = -1, i3 = -1;
  auto ins = [&](float v, int e) {
    if (v > l1 || (v == l1 && e < i1)) { l3=l2; i3=i2; l2=l1; i2=i1; l1=v; i1=e; }
    else if (v > l2 || (v == l2 && e < i2)) { l3=l2; i3=i2; l2=v; i2=e; }
    else if (v > l3 || (v == l3 && e < i3)) { l3=v; i3=e; }
  };
  #pragma unroll
  for (int j = 0; j < 8; ++j) {
    int e = prt * 8 + j;
    ins(lv[j] + bias[e], e);
  }
  #pragma unroll
  for (int m = 1; m <= 8; m <<= 1) {
    float a1 = __shfl_xor(l1, m), a2 = __shfl_xor(l2, m), a3 = __shfl_xor(l3, m);
    int   b1i = __shfl_xor(i1, m), b2i = __shfl_xor(i2, m), b3i = __shfl_xor(i3, m);
    ins(a1, b1i); ins(a2, b2i); ins(a3, b3i);
  }
  if (prt == 0) {
    int fl = ((l1 - l2) < TAU) || ((l2 - l3) < TAU);
    flags[grow] = fl;
    out[(size_t)grow * 2 + 0] = 1.f / (1.f + __expf(-l1));
    out[(size_t)grow * 2 + 1] = 1.f / (1.f + __expf(-l2));
    out[(size_t)N_ROWS * 2 + (size_t)grow * 2 + 0] = (float)i1;
    out[(size_t)N_ROWS * 2 + (size_t)grow * 2 + 1] = (float)i2;
  }
}

// ---------------- kernel 2: exact f64 fixup for flagged rows (parallel) ----------------
__global__ __launch_bounds__(1024) void k2_fix(
    const float* __restrict__ x, const float* __restrict__ W,
    const float* __restrict__ bias, const int* __restrict__ flags,
    float* __restrict__ out)
{
  __shared__ double lgs[E_EXP];
  const int t    = threadIdx.x;        // 1024 threads = 16 waves
  const int wvi  = t >> 6, lane = t & 63;
  const int e    = wvi * 8 + (lane >> 3);
  const int sub  = lane & 7;
  const int rbase = blockIdx.x * 8;

  for (int rr = 0; rr < 8; ++rr) {
    const int row = rbase + rr;
    if (!flags[row]) continue;
    const float* xr = x + (size_t)row * D_DIM;
    const float* wr = W + (size_t)e * D_DIM;
    double a0 = 0.0, a1 = 0.0, a2 = 0.0, a3 = 0.0;
    for (int j = 0; j < 128; ++j) {
      const int c4 = (j * 8 + sub) * 4;
      f32x4 xv = *(const f32x4*)(xr + c4);
      f32x4 wvv = *(const f32x4*)(wr + c4);
      a0 += (double)xv[0] * wvv[0];
      a1 += (double)xv[1] * wvv[1];
      a2 += (double)xv[2] * wvv[2];
      a3 += (double)xv[3] * wvv[3];
    }
    double acc = (a0 + a1) + (a2 + a3);
    #pragma unroll
    for (int m = 1; m <= 4; m <<= 1) acc += __shfl_xor(acc, m);
    if (sub == 0) lgs[e] = acc + (double)bias[e];
    __syncthreads();
    if (t == 0) {
      double l1 = -1e300, l2 = -1e300; int i1 = -1, i2 = -1;
      for (int ee = 0; ee < E_EXP; ++ee) {
        double v = lgs[ee];
        if (v > l1) { l2 = l1; i2 = i1; l1 = v; i1 = ee; }
        else if (v > l2) { l2 = v; i2 = ee; }
      }
      out[(size_t)row * 2 + 0] = (float)(1.0 / (1.0 + exp(-l1)));
      out[(size_t)row * 2 + 1] = (float)(1.0 / (1.0 + exp(-l2)));
      out[(size_t)N_ROWS * 2 + (size_t)row * 2 + 0] = (float)i1;
      out[(size_t)N_ROWS * 2 + (size_t)row * 2 + 1] = (float)i2;
    }
    __syncthreads();
  }
}

extern "C" void kernel_launch(void* const* d_in, const int* in_sizes, int n_in,
                              void* d_out, int out_size, void* d_ws, size_t ws_size,
                              hipStream_t stream) {
  const float* x  = (const float*)d_in[0];
  const float* Wm = (const float*)d_in[1];
  const float* b  = (const float*)d_in[2];
  float* out = (float*)d_out;

  uint16_t* wt   = (uint16_t*)d_ws;                            // 2 MiB tiled W (h+l)
  int*      flags = (int*)((uint8_t*)d_ws + 2u * 1024 * 1024); // 64 KiB
  float*    part = (float*)((uint8_t*)d_ws + 4u * 1024 * 1024);// 33.5 MiB partials

  k0_split<<<dim3(256), dim3(256), 0, stream>>>(Wm, wt);
  k1_main<<<dim3((N_ROWS / BM) * KSPLIT), dim3(512), 0, stream>>>(x, wt, part);
  k3_reduce<<<dim3(N_ROWS / 32), dim3(512), 0, stream>>>(part, b, out, flags);
  k2_fix<<<dim3(N_ROWS / 8), dim3(1024), 0, stream>>>(x, Wm, b, flags, out);
}

// Round 11
// 190.163 us; speedup vs baseline: 2.2635x; 2.2635x over previous
//
#include <hip/hip_runtime.h>
#include <stdint.h>
#include <math.h>

#define N_ROWS 16384
#define D_DIM  4096
#define E_EXP  128
#define BM     32
#define BKR    128              // k per round
#define KSPLIT 2
#define KCHUNK (D_DIM / KSPLIT) // 2048
#define NR     (KCHUNK / BKR)   // 16 rounds per block
#define TAU    2.5e-4f

typedef short  short8 __attribute__((ext_vector_type(8)));
typedef float  f32x4  __attribute__((ext_vector_type(4)));

__device__ __forceinline__ uint32_t bf16_rne(float f) {
  uint32_t u = __builtin_bit_cast(uint32_t, f);
  return (u + 0x7fffu + ((u >> 16) & 1u)) >> 16;
}

// ---------------- kernel 0: split W into bf16 hi/lo, FRAGMENT-TILED ----------------
// blk = (eg*128 + kc)*2 + hl ; within blk lane l: W[eg*16+(l&15)][kc*32+(l>>4)*8 ..+8]
__global__ __launch_bounds__(256) void k0_split(const float* __restrict__ W,
                                                uint16_t* __restrict__ wt) {
  const int b  = blockIdx.x;       // 256 blocks
  const int t  = threadIdx.x;      // 256 threads
  const int eg  = b >> 5;          // 0..7
  const int kcg = b & 31;
  const int kc  = kcg * 4 + (t >> 6);   // 0..127
  const int lane = t & 63;
  const int e  = eg * 16 + (lane & 15);
  const int k0 = kc * 32 + (lane >> 4) * 8;

  const float* src = W + (size_t)e * D_DIM + k0;
  f32x4 w0 = *(const f32x4*)src;
  f32x4 w1 = *(const f32x4*)(src + 4);
  float wf[8] = {w0[0], w0[1], w0[2], w0[3], w1[0], w1[1], w1[2], w1[3]};

  uint16_t h[8], l[8];
  #pragma unroll
  for (int j = 0; j < 8; ++j) {
    uint32_t hh = bf16_rne(wf[j]);
    float hf = __builtin_bit_cast(float, hh << 16);
    h[j] = (uint16_t)hh;
    l[j] = (uint16_t)bf16_rne(wf[j] - hf);
  }
  const size_t blkh = ((size_t)(eg * 128 + kc) * 2 + 0) * 512;  // elements
  const size_t blkl = ((size_t)(eg * 128 + kc) * 2 + 1) * 512;
  *(short8*)(wt + blkh + lane * 8) = *(const short8*)h;
  *(short8*)(wt + blkl + lane * 8) = *(const short8*)l;
}

// ---------------- kernel 1: K-split split-bf16 MFMA GEMM -> f32 partials ----------------
// 1024 blocks (512 row-tiles x 2 k-chunks), 512 threads = 8 waves, 16 rounds/block.
// Register-lean (<=64 VGPR target => 8 waves/SIMD, 4 blocks/CU).
__global__ __launch_bounds__(512, 8) void k1_main(
    const float* __restrict__ x, const uint16_t* __restrict__ wt,
    float* __restrict__ part)
{
  __shared__ __align__(16) uint8_t smem[32768];   // 2 x 16KB staging

  const int t    = threadIdx.x;
  const int lane = t & 63;
  const int wv   = __builtin_amdgcn_readfirstlane(t >> 6);
  const int bid  = blockIdx.x;
  const int rt   = bid >> 1;       // row tile 0..511
  const int ks   = bid & 1;        // k chunk 0..1
  const int row0 = rt * BM;
  const int kb0  = ks * KCHUNK;

  // ---- X staging map ----
  const int srow = t >> 4;        // 0..31
  const int skg  = t & 15;        // k-group of 8 within 128
  const float* xp = x + (size_t)(row0 + srow) * D_DIM + kb0 + skg * 8;

  // ---- LDS write map ----
  const int s_w = skg >> 2, gg_w = skg & 3, rr_w = srow & 15, rg_w = srow >> 4;
  const int p_w  = gg_w * 16 + (rr_w ^ (gg_w << 1) ^ s_w);
  const int wa_h = (s_w * 4 + rg_w * 2 + 0) * 1024 + p_w * 16;
  const int wa_l = wa_h + 1024;

  // ---- LDS read map ----
  const int ggr = lane >> 4, rrr = lane & 15;
  const int p_r0 = ggr * 16 + (rrr ^ (ggr << 1));   // step s: slot = p_r0 ^ s

  // ---- W tiled fragment pointer ----
  const short8* Wt8 = (const short8*)wt;
  const int ccol = lane & 15;

  f32x4 acc[2] = {};

  // x prefetch 2-deep
  f32x4 xa0, xa1, xb0, xb1;
  xa0 = *((const f32x4*)xp + 0); xa1 = *((const f32x4*)xp + 1);
  xb0 = *((const f32x4*)(xp + BKR) + 0); xb1 = *((const f32x4*)(xp + BKR) + 1);

  #pragma unroll 2
  for (int r = 0; r < NR; ++r) {
    // 1) convert xa -> bf16 h/l, write LDS buf[r&1]
    float xf[8] = {xa0[0], xa0[1], xa0[2], xa0[3], xa1[0], xa1[1], xa1[2], xa1[3]};
    uint32_t hpk[4], lpk[4];
    #pragma unroll
    for (int j = 0; j < 4; ++j) {
      uint32_t h0 = bf16_rne(xf[2*j]), h1 = bf16_rne(xf[2*j+1]);
      float h0f = __builtin_bit_cast(float, h0 << 16);
      float h1f = __builtin_bit_cast(float, h1 << 16);
      uint32_t l0 = bf16_rne(xf[2*j] - h0f), l1 = bf16_rne(xf[2*j+1] - h1f);
      hpk[j] = h0 | (h1 << 16);
      lpk[j] = l0 | (l1 << 16);
    }
    uint8_t* buf = smem + (r & 1) * 16384;
    *(uint4*)(buf + wa_h) = make_uint4(hpk[0], hpk[1], hpk[2], hpk[3]);
    *(uint4*)(buf + wa_l) = make_uint4(lpk[0], lpk[1], lpk[2], lpk[3]);

    // 2) rotate x pipeline; issue load for round r+2
    xa0 = xb0; xa1 = xb1;
    if (r + 2 < NR) {
      const f32x4* np = (const f32x4*)(xp + (size_t)(r + 2) * BKR);
      xb0 = np[0]; xb1 = np[1];
    }

    // 3) LDS writes visible; barrier
    asm volatile("s_waitcnt lgkmcnt(0)" ::: "memory");
    __builtin_amdgcn_s_barrier();

    // 4) MFMA round r: W loaded per k-step (transient regs, L2-resident tiled W)
    #pragma unroll
    for (int s = 0; s < 4; ++s) {
      const int pr = p_r0 ^ s;
      const int kcc = ks * (KCHUNK / 32) + r * 4 + s;   // global k-chunk-of-32
      const size_t bb = ((size_t)(wv * 128 + kcc) * 2) * 64 + lane;
      const short8 bh = Wt8[bb];
      const short8 bl = Wt8[bb + 64];
      #pragma unroll
      for (int rg = 0; rg < 2; ++rg) {
        const uint8_t* fb = buf + (s * 4 + rg * 2) * 1024 + pr * 16;
        short8 ah = *(const short8*)fb;
        short8 al = *(const short8*)(fb + 1024);
        acc[rg] = __builtin_amdgcn_mfma_f32_16x16x32_bf16(ah, bh, acc[rg], 0, 0, 0);
        acc[rg] = __builtin_amdgcn_mfma_f32_16x16x32_bf16(al, bh, acc[rg], 0, 0, 0);
        acc[rg] = __builtin_amdgcn_mfma_f32_16x16x32_bf16(ah, bl, acc[rg], 0, 0, 0);
      }
    }
  }

  // ---- epilogue: store partials part[ks][row][e] ----
  float* dst = part + ((size_t)ks * N_ROWS + row0) * E_EXP;
  #pragma unroll
  for (int rg = 0; rg < 2; ++rg)
    #pragma unroll
    for (int i = 0; i < 4; ++i) {
      int row = rg * 16 + ggr * 4 + i;
      int e = wv * 16 + ccol;
      dst[(size_t)row * E_EXP + e] = acc[rg][i];
    }
}

// ---------------- kernel 3: reduce partials + bias + sigmoid + top-3 + flags ----------------
__global__ __launch_bounds__(512) void k3_reduce(
    const float* __restrict__ part, const float* __restrict__ bias,
    float* __restrict__ out, int* __restrict__ flags)
{
  const int t = threadIdx.x;
  const int row = t >> 4, prt = t & 15;     // 32 rows/block, 16 threads/row
  const int grow = blockIdx.x * 32 + row;
  const float* pp = part + (size_t)grow * E_EXP + prt * 8;

  f32x4 s0 = {}, s1 = {};
  #pragma unroll
  for (int ks = 0; ks < KSPLIT; ++ks) {
    const float* q = pp + (size_t)ks * N_ROWS * E_EXP;
    f32x4 a = *(const f32x4*)q;
    f32x4 b = *(const f32x4*)(q + 4);
    s0 += a; s1 += b;
  }
  float lv[8] = {s0[0], s0[1], s0[2], s0[3], s1[0], s1[1], s1[2], s1[3]};

  float l1 = -3e38f, l2 = -3e38f, l3 = -3e38f;
  int   i1 = -1, i2 = -1, i3 = -1;
  auto ins = [&](float v, int e) {
    if (v > l1 || (v == l1 && e < i1)) { l3=l2; i3=i2; l2=l1; i2=i1; l1=v; i1=e; }
    else if (v > l2 || (v == l2 && e < i2)) { l3=l2; i3=i2; l2=v; i2=e; }
    else if (v > l3 || (v == l3 && e < i3)) { l3=v; i3=e; }
  };
  #pragma unroll
  for (int j = 0; j < 8; ++j) {
    int e = prt * 8 + j;
    ins(lv[j] + bias[e], e);
  }
  #pragma unroll
  for (int m = 1; m <= 8; m <<= 1) {
    float a1 = __shfl_xor(l1, m), a2 = __shfl_xor(l2, m), a3 = __shfl_xor(l3, m);
    int   b1i = __shfl_xor(i1, m), b2i = __shfl_xor(i2, m), b3i = __shfl_xor(i3, m);
    ins(a1, b1i); ins(a2, b2i); ins(a3, b3i);
  }
  if (prt == 0) {
    int fl = ((l1 - l2) < TAU) || ((l2 - l3) < TAU);
    flags[grow] = fl;
    out[(size_t)grow * 2 + 0] = 1.f / (1.f + __expf(-l1));
    out[(size_t)grow * 2 + 1] = 1.f / (1.f + __expf(-l2));
    out[(size_t)N_ROWS * 2 + (size_t)grow * 2 + 0] = (float)i1;
    out[(size_t)N_ROWS * 2 + (size_t)grow * 2 + 1] = (float)i2;
  }
}

// ---------------- kernel 2: exact f64 fixup for flagged rows (parallel) ----------------
__global__ __launch_bounds__(1024) void k2_fix(
    const float* __restrict__ x, const float* __restrict__ W,
    const float* __restrict__ bias, const int* __restrict__ flags,
    float* __restrict__ out)
{
  __shared__ double lgs[E_EXP];
  const int t    = threadIdx.x;        // 1024 threads = 16 waves
  const int wvi  = t >> 6, lane = t & 63;
  const int e    = wvi * 8 + (lane >> 3);
  const int sub  = lane & 7;
  const int rbase = blockIdx.x * 8;

  for (int rr = 0; rr < 8; ++rr) {
    const int row = rbase + rr;
    if (!flags[row]) continue;
    const float* xr = x + (size_t)row * D_DIM;
    const float* wr = W + (size_t)e * D_DIM;
    double a0 = 0.0, a1 = 0.0, a2 = 0.0, a3 = 0.0;
    for (int j = 0; j < 128; ++j) {
      const int c4 = (j * 8 + sub) * 4;
      f32x4 xv = *(const f32x4*)(xr + c4);
      f32x4 wvv = *(const f32x4*)(wr + c4);
      a0 += (double)xv[0] * wvv[0];
      a1 += (double)xv[1] * wvv[1];
      a2 += (double)xv[2] * wvv[2];
      a3 += (double)xv[3] * wvv[3];
    }
    double acc = (a0 + a1) + (a2 + a3);
    #pragma unroll
    for (int m = 1; m <= 4; m <<= 1) acc += __shfl_xor(acc, m);
    if (sub == 0) lgs[e] = acc + (double)bias[e];
    __syncthreads();
    if (t == 0) {
      double l1 = -1e300, l2 = -1e300; int i1 = -1, i2 = -1;
      for (int ee = 0; ee < E_EXP; ++ee) {
        double v = lgs[ee];
        if (v > l1) { l2 = l1; i2 = i1; l1 = v; i1 = ee; }
        else if (v > l2) { l2 = v; i2 = ee; }
      }
      out[(size_t)row * 2 + 0] = (float)(1.0 / (1.0 + exp(-l1)));
      out[(size_t)row * 2 + 1] = (float)(1.0 / (1.0 + exp(-l2)));
      out[(size_t)N_ROWS * 2 + (size_t)row * 2 + 0] = (float)i1;
      out[(size_t)N_ROWS * 2 + (size_t)row * 2 + 1] = (float)i2;
    }
    __syncthreads();
  }
}

extern "C" void kernel_launch(void* const* d_in, const int* in_sizes, int n_in,
                              void* d_out, int out_size, void* d_ws, size_t ws_size,
                              hipStream_t stream) {
  const float* x  = (const float*)d_in[0];
  const float* Wm = (const float*)d_in[1];
  const float* b  = (const float*)d_in[2];
  float* out = (float*)d_out;

  uint16_t* wt   = (uint16_t*)d_ws;                            // 2 MiB tiled W (h+l)
  int*      flags = (int*)((uint8_t*)d_ws + 2u * 1024 * 1024); // 64 KiB
  float*    part = (float*)((uint8_t*)d_ws + 4u * 1024 * 1024);// 16.8 MiB partials

  k0_split<<<dim3(256), dim3(256), 0, stream>>>(Wm, wt);
  k1_main<<<dim3((N_ROWS / BM) * KSPLIT), dim3(512), 0, stream>>>(x, wt, part);
  k3_reduce<<<dim3(N_ROWS / 32), dim3(512), 0, stream>>>(part, b, out, flags);
  k2_fix<<<dim3(N_ROWS / 8), dim3(1024), 0, stream>>>(x, Wm, b, flags, out);
}

// Round 12
// 170.831 us; speedup vs baseline: 2.5197x; 1.1132x over previous
//
#include <hip/hip_runtime.h>
#include <stdint.h>
#include <math.h>

#define N_ROWS 16384
#define D_DIM  4096
#define E_EXP  128
#define BM     32
#define BKR    128              // k per round
#define NR     (D_DIM / BKR)    // 32 rounds
#define TAU    2.5e-4f

typedef short  short8 __attribute__((ext_vector_type(8)));
typedef float  f32x4  __attribute__((ext_vector_type(4)));

__device__ __forceinline__ uint32_t bf16_rne(float f) {
  uint32_t u = __builtin_bit_cast(uint32_t, f);
  return (u + 0x7fffu + ((u >> 16) & 1u)) >> 16;
}

// ---------------- kernel 0: split W into bf16 hi/lo, FRAGMENT-TILED ----------------
// blk = (eg*128 + kc)*2 + hl ; within blk lane l: W[eg*16+(l&15)][kc*32+(l>>4)*8 ..+8]
__global__ __launch_bounds__(256) void k0_split(const float* __restrict__ W,
                                                uint16_t* __restrict__ wt) {
  const int b  = blockIdx.x;       // 256 blocks
  const int t  = threadIdx.x;      // 256 threads
  const int eg  = b >> 5;          // 0..7
  const int kcg = b & 31;
  const int kc  = kcg * 4 + (t >> 6);   // 0..127
  const int lane = t & 63;
  const int e  = eg * 16 + (lane & 15);
  const int k0 = kc * 32 + (lane >> 4) * 8;

  const float* src = W + (size_t)e * D_DIM + k0;
  f32x4 w0 = *(const f32x4*)src;
  f32x4 w1 = *(const f32x4*)(src + 4);
  float wf[8] = {w0[0], w0[1], w0[2], w0[3], w1[0], w1[1], w1[2], w1[3]};

  uint16_t h[8], l[8];
  #pragma unroll
  for (int j = 0; j < 8; ++j) {
    uint32_t hh = bf16_rne(wf[j]);
    float hf = __builtin_bit_cast(float, hh << 16);
    h[j] = (uint16_t)hh;
    l[j] = (uint16_t)bf16_rne(wf[j] - hf);
  }
  const size_t blkh = ((size_t)(eg * 128 + kc) * 2 + 0) * 512;  // elements
  const size_t blkl = ((size_t)(eg * 128 + kc) * 2 + 1) * 512;
  *(short8*)(wt + blkh + lane * 8) = *(const short8*)h;
  *(short8*)(wt + blkl + lane * 8) = *(const short8*)l;
}

// ---------------- kernel 1: phase-pipelined split-bf16 MFMA GEMM + top3 + flags ----
// 512 threads = 8 waves; BM=32 rows/block; wave owns 16 experts.
// Round r interval: MFMA(tile r) || convert(tile r+1) || stores -> ONE barrier.
__global__ __launch_bounds__(512, 4) void k1_main(
    const float* __restrict__ x, const uint16_t* __restrict__ wt,
    const float* __restrict__ bias, float* __restrict__ out, int* __restrict__ flags)
{
  __shared__ __align__(16) uint8_t smem[32768];   // 2 x 16KB frag buffers
  float* Ld = (float*)smem;

  const int t    = threadIdx.x;
  const int lane = t & 63;
  const int wv   = __builtin_amdgcn_readfirstlane(t >> 6);
  const int row0 = blockIdx.x * BM;

  // ---- X staging map ----
  const int srow = t >> 4;        // 0..31
  const int skg  = t & 15;        // k-group of 8 within 128
  const float* xp = x + (size_t)(row0 + srow) * D_DIM + skg * 8;

  // ---- LDS write map ----
  const int s_w = skg >> 2, gg_w = skg & 3, rr_w = srow & 15, rg_w = srow >> 4;
  const int p_w  = gg_w * 16 + (rr_w ^ (gg_w << 1) ^ s_w);
  const int wa_h = (s_w * 4 + rg_w * 2 + 0) * 1024 + p_w * 16;
  const int wa_l = wa_h + 1024;

  // ---- LDS read map ----
  const int ggr = lane >> 4, rrr = lane & 15;
  const int p_r0 = ggr * 16 + (rrr ^ (ggr << 1));   // step s: slot = p_r0 ^ s

  // ---- W tiled fragment pointer ----
  const short8* Wt8 = (const short8*)wt;
  const int ccol = lane & 15;

  f32x4 acc[2] = {};

  // ---- prologue: tile 0 convert -> buf0; xa=tile1, xb=tile2, xc=tile3; Wc=W(0) ----
  {
    f32x4 t0 = *((const f32x4*)xp + 0), t1 = *((const f32x4*)xp + 1);
    float xf[8] = {t0[0], t0[1], t0[2], t0[3], t1[0], t1[1], t1[2], t1[3]};
    uint32_t hpk[4], lpk[4];
    #pragma unroll
    for (int j = 0; j < 4; ++j) {
      uint32_t h0 = bf16_rne(xf[2*j]), h1 = bf16_rne(xf[2*j+1]);
      float h0f = __builtin_bit_cast(float, h0 << 16);
      float h1f = __builtin_bit_cast(float, h1 << 16);
      uint32_t l0 = bf16_rne(xf[2*j] - h0f), l1 = bf16_rne(xf[2*j+1] - h1f);
      hpk[j] = h0 | (h1 << 16);
      lpk[j] = l0 | (l1 << 16);
    }
    *(uint4*)(smem + wa_h) = make_uint4(hpk[0], hpk[1], hpk[2], hpk[3]);
    *(uint4*)(smem + wa_l) = make_uint4(lpk[0], lpk[1], lpk[2], lpk[3]);
  }
  f32x4 xa0, xa1, xb0, xb1, xc0, xc1;
  xa0 = *((const f32x4*)(xp + 1 * BKR) + 0); xa1 = *((const f32x4*)(xp + 1 * BKR) + 1);
  xb0 = *((const f32x4*)(xp + 2 * BKR) + 0); xb1 = *((const f32x4*)(xp + 2 * BKR) + 1);
  xc0 = *((const f32x4*)(xp + 3 * BKR) + 0); xc1 = *((const f32x4*)(xp + 3 * BKR) + 1);

  short8 Wc[8], Wn[8];
  {
    const size_t b0 = ((size_t)(wv * 128) * 2) * 64 + lane;
    #pragma unroll
    for (int q = 0; q < 8; ++q) Wc[q] = Wt8[b0 + (size_t)q * 64];
  }
  asm volatile("s_waitcnt lgkmcnt(0)" ::: "memory");
  __builtin_amdgcn_s_barrier();

  #pragma unroll 2
  for (int r = 0; r < NR; ++r) {
    uint8_t* rbuf = smem + (r & 1) * 16384;          // MFMA reads tile r here
    uint8_t* wbuf = smem + ((r + 1) & 1) * 16384;    // convert writes tile r+1 here

    // 1) issue W(r+1)
    if (r + 1 < NR) {
      const size_t nb = ((size_t)(wv * 128 + (r + 1) * 4) * 2) * 64 + lane;
      #pragma unroll
      for (int q = 0; q < 8; ++q) Wn[q] = Wt8[nb + (size_t)q * 64];
    }

    // 2) convert xa (tile r+1) -> regs (VALU fills MFMA-phase latency shadows)
    uint32_t hpk[4], lpk[4];
    if (r + 1 < NR) {
      float xf[8] = {xa0[0], xa0[1], xa0[2], xa0[3], xa1[0], xa1[1], xa1[2], xa1[3]};
      #pragma unroll
      for (int j = 0; j < 4; ++j) {
        uint32_t h0 = bf16_rne(xf[2*j]), h1 = bf16_rne(xf[2*j+1]);
        float h0f = __builtin_bit_cast(float, h0 << 16);
        float h1f = __builtin_bit_cast(float, h1 << 16);
        uint32_t l0 = bf16_rne(xf[2*j] - h0f), l1 = bf16_rne(xf[2*j+1] - h1f);
        hpk[j] = h0 | (h1 << 16);
        lpk[j] = l0 | (l1 << 16);
      }
    }

    // 3) MFMA round r from rbuf + Wc
    #pragma unroll
    for (int s = 0; s < 4; ++s) {
      const int pr = p_r0 ^ s;
      const short8 bh = Wc[s * 2 + 0], bl = Wc[s * 2 + 1];
      #pragma unroll
      for (int rg = 0; rg < 2; ++rg) {
        const uint8_t* fb = rbuf + (s * 4 + rg * 2) * 1024 + pr * 16;
        short8 ah = *(const short8*)fb;
        short8 al = *(const short8*)(fb + 1024);
        acc[rg] = __builtin_amdgcn_mfma_f32_16x16x32_bf16(ah, bh, acc[rg], 0, 0, 0);
        acc[rg] = __builtin_amdgcn_mfma_f32_16x16x32_bf16(al, bh, acc[rg], 0, 0, 0);
        acc[rg] = __builtin_amdgcn_mfma_f32_16x16x32_bf16(ah, bl, acc[rg], 0, 0, 0);
      }
    }

    // 4) store tile r+1 frags into the other buffer (no intra-round hazard)
    if (r + 1 < NR) {
      *(uint4*)(wbuf + wa_h) = make_uint4(hpk[0], hpk[1], hpk[2], hpk[3]);
      *(uint4*)(wbuf + wa_l) = make_uint4(lpk[0], lpk[1], lpk[2], lpk[3]);
    }

    // 5) rotate x pipeline; issue tile r+4
    xa0 = xb0; xa1 = xb1; xb0 = xc0; xb1 = xc1;
    if (r + 4 < NR) {
      const f32x4* np = (const f32x4*)(xp + (size_t)(r + 4) * BKR);
      xc0 = np[0]; xc1 = np[1];
    }

    // 6) one barrier per round
    asm volatile("s_waitcnt lgkmcnt(0)" ::: "memory");
    __builtin_amdgcn_s_barrier();

    // 7) rotate W
    #pragma unroll
    for (int q = 0; q < 8; ++q) Wc[q] = Wn[q];
  }

  // ---- epilogue: logits -> LDS [32][128] ----
  float b0 = bias[wv * 16 + ccol];
  __syncthreads();
  #pragma unroll
  for (int rg = 0; rg < 2; ++rg)
    #pragma unroll
    for (int i = 0; i < 4; ++i) {
      int row = rg * 16 + ggr * 4 + i;
      int e = wv * 16 + ccol;
      Ld[row * 128 + e] = acc[rg][i] + b0;
    }
  __syncthreads();

  // ---- top-3 per row: 16 threads/row, 8 logits each, shfl merge ----
  {
    const int row = t >> 4, part = t & 15;
    float l1 = -3e38f, l2 = -3e38f, l3 = -3e38f;
    int   i1 = -1, i2 = -1, i3 = -1;
    auto ins = [&](float v, int e) {
      if (v > l1 || (v == l1 && e < i1)) { l3=l2; i3=i2; l2=l1; i2=i1; l1=v; i1=e; }
      else if (v > l2 || (v == l2 && e < i2)) { l3=l2; i3=i2; l2=v; i2=e; }
      else if (v > l3 || (v == l3 && e < i3)) { l3=v; i3=e; }
    };
    #pragma unroll
    for (int j = 0; j < 2; ++j) {
      const float* pp = Ld + row * 128 + part * 8 + j * 4;
      f32x4 v = *(const f32x4*)pp;
      int eb = part * 8 + j * 4;
      ins(v[0], eb); ins(v[1], eb + 1); ins(v[2], eb + 2); ins(v[3], eb + 3);
    }
    #pragma unroll
    for (int m = 1; m <= 8; m <<= 1) {
      float a1 = __shfl_xor(l1, m), a2 = __shfl_xor(l2, m), a3 = __shfl_xor(l3, m);
      int   b1i = __shfl_xor(i1, m), b2i = __shfl_xor(i2, m), b3i = __shfl_xor(i3, m);
      ins(a1, b1i); ins(a2, b2i); ins(a3, b3i);
    }
    if (part == 0) {
      int grow = row0 + row;
      int fl = ((l1 - l2) < TAU) || ((l2 - l3) < TAU);
      flags[grow] = fl;
      out[(size_t)grow * 2 + 0] = 1.f / (1.f + __expf(-l1));
      out[(size_t)grow * 2 + 1] = 1.f / (1.f + __expf(-l2));
      out[(size_t)N_ROWS * 2 + (size_t)grow * 2 + 0] = (float)i1;
      out[(size_t)N_ROWS * 2 + (size_t)grow * 2 + 1] = (float)i2;
    }
  }
}

// ---------------- kernel 2: exact f64 fixup for flagged rows (parallel) ----------------
__global__ __launch_bounds__(1024) void k2_fix(
    const float* __restrict__ x, const float* __restrict__ W,
    const float* __restrict__ bias, const int* __restrict__ flags,
    float* __restrict__ out)
{
  __shared__ double lgs[E_EXP];
  const int t    = threadIdx.x;        // 1024 threads = 16 waves
  const int wvi  = t >> 6, lane = t & 63;
  const int e    = wvi * 8 + (lane >> 3);
  const int sub  = lane & 7;
  const int rbase = blockIdx.x * 8;

  for (int rr = 0; rr < 8; ++rr) {
    const int row = rbase + rr;
    if (!flags[row]) continue;
    const float* xr = x + (size_t)row * D_DIM;
    const float* wr = W + (size_t)e * D_DIM;
    double a0 = 0.0, a1 = 0.0, a2 = 0.0, a3 = 0.0;
    for (int j = 0; j < 128; ++j) {
      const int c4 = (j * 8 + sub) * 4;
      f32x4 xv = *(const f32x4*)(xr + c4);
      f32x4 wvv = *(const f32x4*)(wr + c4);
      a0 += (double)xv[0] * wvv[0];
      a1 += (double)xv[1] * wvv[1];
      a2 += (double)xv[2] * wvv[2];
      a3 += (double)xv[3] * wvv[3];
    }
    double acc = (a0 + a1) + (a2 + a3);
    #pragma unroll
    for (int m = 1; m <= 4; m <<= 1) acc += __shfl_xor(acc, m);
    if (sub == 0) lgs[e] = acc + (double)bias[e];
    __syncthreads();
    if (t == 0) {
      double l1 = -1e300, l2 = -1e300; int i1 = -1, i2 = -1;
      for (int ee = 0; ee < E_EXP; ++ee) {
        double v = lgs[ee];
        if (v > l1) { l2 = l1; i2 = i1; l1 = v; i1 = ee; }
        else if (v > l2) { l2 = v; i2 = ee; }
      }
      out[(size_t)row * 2 + 0] = (float)(1.0 / (1.0 + exp(-l1)));
      out[(size_t)row * 2 + 1] = (float)(1.0 / (1.0 + exp(-l2)));
      out[(size_t)N_ROWS * 2 + (size_t)row * 2 + 0] = (float)i1;
      out[(size_t)N_ROWS * 2 + (size_t)row * 2 + 1] = (float)i2;
    }
    __syncthreads();
  }
}

extern "C" void kernel_launch(void* const* d_in, const int* in_sizes, int n_in,
                              void* d_out, int out_size, void* d_ws, size_t ws_size,
                              hipStream_t stream) {
  const float* x  = (const float*)d_in[0];
  const float* Wm = (const float*)d_in[1];
  const float* b  = (const float*)d_in[2];
  float* out = (float*)d_out;

  uint16_t* wt = (uint16_t*)d_ws;                          // 2 MiB tiled W (h+l)
  int* flags = (int*)((uint8_t*)d_ws + 2u * 1024 * 1024);  // 64 KiB

  k0_split<<<dim3(256), dim3(256), 0, stream>>>(Wm, wt);
  k1_main<<<dim3(N_ROWS / BM), dim3(512), 0, stream>>>(x, wt, b, out, flags);
  k2_fix<<<dim3(N_ROWS / 8), dim3(1024), 0, stream>>>(x, Wm, b, flags, out);
}